// Round 5
// baseline (1490.256 us; speedup 1.0000x reference)
//
#include <hip/hip_runtime.h>
#include <hip/hip_bf16.h>

// Problem constants
#define TT 2048
#define KK 6
#define EE 32
#define DD 2048
#define FF 1408
#define SS 2
#define CC 384   // TT*KK/EE

typedef __bf16 bf16_t;
typedef __attribute__((ext_vector_type(8))) __bf16 bf16x8;
typedef __attribute__((ext_vector_type(4))) float f32x4;
typedef unsigned int u32;

#define AS1 __attribute__((address_space(1)))
#define AS3 __attribute__((address_space(3)))

__device__ __forceinline__ u32 f2bf(float f) {
    u32 u = __builtin_bit_cast(u32, f);
    return (u + 0x7fffu + ((u >> 16) & 1u)) >> 16;   // RNE, no NaN in data
}
__device__ __forceinline__ u32 pack2(float a, float b) {
    return f2bf(a) | (f2bf(b) << 16);
}
__device__ __forceinline__ float silu_mul(float g, float u) {
    return (g / (1.0f + __expf(-g))) * u;
}

// ---------------- dispatch: pair -> slot (balanced: exactly CC per expert) ----
__global__ void k_dispatch(const int* __restrict__ idx, int* __restrict__ counts,
                           int* __restrict__ tok, int* __restrict__ sop) {
    int p = blockIdx.x * 256 + threadIdx.x;
    if (p >= TT * KK) return;
    int e = idx[p];
    int pos = atomicAdd(&counts[e], 1);
    int slot = e * CC + pos;
    tok[slot] = p / KK;
    sop[p] = slot;
}

// ---------------- gather + fp32->bf16 convert --------------------------------
__global__ void k_gather(const float* __restrict__ x, const int* __restrict__ tok,
                         bf16_t* __restrict__ xall) {
    int row = blockIdx.x;
    int srow = (row < EE * CC) ? tok[row] : (row - EE * CC);
    const float* src = x + (size_t)srow * DD;
    bf16_t* dst = xall + (size_t)row * DD;
    int c0 = threadIdx.x * 8;
    float4 a = *(const float4*)(src + c0);
    float4 b = *(const float4*)(src + c0 + 4);
    uint4 o;
    o.x = pack2(a.x, a.y); o.y = pack2(a.z, a.w);
    o.z = pack2(b.x, b.y); o.w = pack2(b.z, b.w);
    *(uint4*)(dst + c0) = o;
}

// =====================================================================
// Routed grouped GEMM, BK=64, one counted vmcnt per K-step.
// 512 threads (8 waves, 4m x 2n), tile M=384 (whole expert) x N=128.
// B (fp32 weights) read EXACTLY ONCE per expert. A prefetch distance 1
// (2 LDS buffers), B prefetch distance 2 (regs -> LDS, 2 LDS buffers).
// Queue at iter top = [B(t+1):16, A(t):6]; after issuing B(t+2):16 a single
// s_waitcnt vmcnt(16) retires B(t+1)+A(t). A LDS layout is 8-way XOR-swizzled
// via pre-swizzled glds source (chunk ^= row&7): frag ds_read_b128 2-way (free).
// =====================================================================
template<bool FUSED>
__global__ __launch_bounds__(512) void k_gemm_r(
    const bf16_t* __restrict__ Aall, const float* __restrict__ Br,
    bf16_t* __restrict__ Out, int Kdim, int Bstr, int Ostr, int NB)
{
    const int lin = blockIdx.x;
    const int xcd = lin & 7, jj = lin >> 3;
    const int e = xcd + 8 * (jj / NB);     // expert pinned to XCD e%8
    const int nblk = jj % NB;

    const bf16_t* A = Aall + (size_t)e * CC * Kdim;
    const float* Bbase = Br + (size_t)e * Kdim * Bstr;

    const int tid = threadIdx.x;
    const int lane = tid & 63, wid = tid >> 6;
    const int m_base = (wid >> 1) * 96, wn = wid & 1;
    const int l15 = lane & 15, lq = lane >> 4;
    const int arow8 = tid >> 3, achunk = tid & 7;   // A-stage: row within stripe, 16B chunk
    const int bn = tid & 127, kb = (tid >> 7) * 16; // B-stage: col, k-offset {0,16,32,48}

    const float* bsrc;
    bf16_t* Cout;
    if (FUSED) {   // N-tile = 64 gate cols + 64 up cols (same local index)
        bsrc = Bbase + ((bn & 64) ? FF : 0) + nblk * 64 + (bn & 63);
        Cout = Out + (size_t)e * CC * Ostr + nblk * 64;
    } else {
        bsrc = Bbase + nblk * 128 + bn;
        Cout = Out + (size_t)e * CC * Ostr + nblk * 128;
    }

    __shared__ __align__(16) bf16_t As[2][384 * 64];   // 2 x 48 KB
    __shared__ __align__(16) bf16_t Bs[2][128 * 72];   // 2 x 18 KB (72 = 64 + 8 pad)

    f32x4 acc[6][4] = {};
    const int ks = Kdim >> 6;   // 32 (gate_up) or 22 (down), both even

    auto stageA = [&](int kt, bf16_t* dst) {
        const int k0 = kt << 6;
        #pragma unroll
        for (int i = 0; i < 6; ++i) {
            const int row = i * 64 + arow8;
            const int c = achunk ^ (row & 7);   // pre-swizzled source chunk
            const bf16_t* g = A + (size_t)row * Kdim + (k0 + c * 8);
            AS3 u32* l = (AS3 u32*)(void*)(dst + (size_t)(i * 64 + wid * 8) * 64);
            __builtin_amdgcn_global_load_lds((const AS1 u32*)(const void*)g, l, 16, 0, 0);
        }
    };
    auto loadB = [&](int kt, float* v) {
        const float* sp = bsrc + (size_t)((kt << 6) + kb) * Bstr;
        #pragma unroll
        for (int t = 0; t < 16; ++t) v[t] = sp[(size_t)t * Bstr];
    };
    auto writeB = [&](bf16_t* bbuf, const float* v) {
        uint4 w0, w1;
        w0.x = pack2(v[0], v[1]);   w0.y = pack2(v[2], v[3]);
        w0.z = pack2(v[4], v[5]);   w0.w = pack2(v[6], v[7]);
        w1.x = pack2(v[8], v[9]);   w1.y = pack2(v[10], v[11]);
        w1.z = pack2(v[12], v[13]); w1.w = pack2(v[14], v[15]);
        *(uint4*)(bbuf + (size_t)bn * 72 + kb) = w0;
        *(uint4*)(bbuf + (size_t)bn * 72 + kb + 8) = w1;
    };
    auto compute = [&](const bf16_t* abuf, const bf16_t* bbuf) {
        __builtin_amdgcn_s_setprio(1);
        #pragma unroll
        for (int kh = 0; kh < 2; ++kh) {
            bf16x8 bfr[4];
            #pragma unroll
            for (int j = 0; j < 4; ++j) {
                const int n_ds = FUSED ? (wn * 32 + (j & 1) * 16 + (j >> 1) * 64)
                                       : (wn * 64 + j * 16);
                bfr[j] = *(const bf16x8*)(bbuf + (size_t)(n_ds + l15) * 72 + kh * 32 + lq * 8);
            }
            #pragma unroll
            for (int m = 0; m < 6; ++m) {
                const int row = m_base + m * 16 + l15;
                bf16x8 af = *(const bf16x8*)(abuf + (size_t)row * 64
                               + (size_t)(((kh * 4 + lq) ^ (row & 7)) * 8));
                #pragma unroll
                for (int j = 0; j < 4; ++j)
                    acc[m][j] = __builtin_amdgcn_mfma_f32_16x16x32_bf16(af, bfr[j], acc[m][j], 0, 0, 0);
            }
        }
        __builtin_amdgcn_s_setprio(0);
    };

    float vBa[16], vBb[16];

    // ---- prologue (issue order matches steady-state queue [B(next), A(cur)]) ----
    loadB(0, vBa);
    asm volatile("s_waitcnt vmcnt(0)" ::: "memory");
    writeB(&Bs[0][0], vBa);
    loadB(1, vBb);                         // 16 vm
    stageA(0, &As[0][0]);                  // 6 vm
    asm volatile("s_waitcnt lgkmcnt(0)" ::: "memory");
    __builtin_amdgcn_s_barrier();

    for (int t = 0; t < ks - 2; t += 2) {
        // ---- even iter t: compute As[0], Bs[0] ----
        loadB(t + 2, vBa);
        asm volatile("s_waitcnt vmcnt(16)" ::: "memory");  // retire B(t+1)+A(t)
        asm volatile("s_waitcnt lgkmcnt(0)" ::: "memory");
        __builtin_amdgcn_s_barrier();
        stageA(t + 1, &As[1][0]);
        compute(&As[0][0], &Bs[0][0]);
        writeB(&Bs[1][0], vBb);
        // ---- odd iter t+1: compute As[1], Bs[1] ----
        loadB(t + 3, vBb);
        asm volatile("s_waitcnt vmcnt(16)" ::: "memory");
        asm volatile("s_waitcnt lgkmcnt(0)" ::: "memory");
        __builtin_amdgcn_s_barrier();
        stageA(t + 2, &As[0][0]);
        compute(&As[1][0], &Bs[1][0]);
        writeB(&Bs[0][0], vBa);
    }

    // ---- tail: iter ks-2 (As[0]/Bs[0]) and ks-1 (As[1]/Bs[1]) ----
    asm volatile("s_waitcnt vmcnt(0)" ::: "memory");       // retire B(ks-1)+A(ks-2)
    asm volatile("s_waitcnt lgkmcnt(0)" ::: "memory");
    __builtin_amdgcn_s_barrier();
    stageA(ks - 1, &As[1][0]);
    compute(&As[0][0], &Bs[0][0]);
    writeB(&Bs[1][0], vBb);
    asm volatile("s_waitcnt vmcnt(0)" ::: "memory");       // A(ks-1)
    asm volatile("s_waitcnt lgkmcnt(0)" ::: "memory");
    __builtin_amdgcn_s_barrier();
    compute(&As[1][0], &Bs[1][0]);

    // ---- epilogue: C/D layout col=lane&15, row=quad*4+reg ----
    if (FUSED) {
        #pragma unroll
        for (int m = 0; m < 6; ++m)
            #pragma unroll
            for (int j = 0; j < 2; ++j) {
                const int n = wn * 32 + j * 16 + l15;
                #pragma unroll
                for (int r = 0; r < 4; ++r) {
                    const int mm = m_base + m * 16 + lq * 4 + r;
                    Cout[(size_t)mm * Ostr + n] = (bf16_t)silu_mul(acc[m][j][r], acc[m][j + 2][r]);
                }
            }
    } else {
        #pragma unroll
        for (int m = 0; m < 6; ++m)
            #pragma unroll
            for (int j = 0; j < 4; ++j) {
                const int n = wn * 64 + j * 16 + l15;
                #pragma unroll
                for (int r = 0; r < 4; ++r) {
                    const int mm = m_base + m * 16 + lq * 4 + r;
                    Cout[(size_t)mm * Ostr + n] = (bf16_t)acc[m][j][r];
                }
            }
    }
}

// =====================================================================
// Shared-expert GEMM, 256 threads (4 waves, 2m x 2n), tile 128 x 128, BK=32.
// Deep pipeline with counted vmcnt (unchanged from R4 - verified).
// =====================================================================
#define BSTR 40
template<bool FUSED>
__global__ __launch_bounds__(256) void k_gemm_s(
    const bf16_t* __restrict__ Ash, const float* __restrict__ Bsh,
    bf16_t* __restrict__ Out, int Kdim, int Bstr, int Ostr, int ash_stride,
    int nkeys, int KQ, int NBs)
{
    const int b = blockIdx.x;
    const int xcd = b & 7, jj = b >> 3;
    const int m = jj / KQ, kq = jj % KQ;
    const int key = kq * 8 + xcd;
    if (key >= nkeys) return;
    const int s = key / NBs, nb = key % NBs;

    const bf16_t* A = Ash + ((size_t)s * ash_stride + (size_t)m * 128) * Kdim;
    const float* Bp = Bsh + (size_t)s * Kdim * Bstr;

    const int tid = threadIdx.x;
    const int lane = tid & 63, wid = tid >> 6;
    const int m_off = (wid >> 1) * 64, wn = wid & 1;
    const int l15 = lane & 15, lq = lane >> 4;
    const int arow = tid >> 2, ac = tid & 3;
    const int bn = tid & 127, kb = (tid >> 7) * 16;

    const float* bsrc;
    bf16_t* Cout;
    if (FUSED) {
        bsrc = Bp + (((tid >> 6) & 1) ? FF : 0) + nb * 64 + (tid & 63);
        Cout = Out + ((size_t)s * TT + (size_t)m * 128) * Ostr + nb * 64;
    } else {
        bsrc = Bp + nb * 128 + bn;
        Cout = Out + ((size_t)s * TT + (size_t)m * 128) * Ostr + nb * 128;
    }

    __shared__ __align__(16) bf16_t As[3][128 * 32];   // 3 x 8 KB
    __shared__ __align__(16) bf16_t Bs[2][128 * BSTR]; // 2 x 10 KB

    f32x4 acc[4][4] = {};
    const int ksteps = Kdim >> 5;   // 64 or 44 (even)

    auto stageA = [&](int kt, bf16_t* dst) {
        const int k0 = kt << 5;
        #pragma unroll
        for (int i = 0; i < 2; ++i) {
            const int row = i * 64 + arow;
            const int cs = ac ^ ((row >> 1) & 3);
            const bf16_t* g = A + (size_t)row * Kdim + (k0 + cs * 8);
            AS3 u32* l = (AS3 u32*)(void*)(dst + (size_t)(i * 64 + wid * 16) * 32);
            __builtin_amdgcn_global_load_lds((const AS1 u32*)(const void*)g, l, 16, 0, 0);
        }
    };
    auto loadB = [&](int kt, float* v) {
        const float* sp = bsrc + (size_t)((kt << 5) + kb) * Bstr;
        #pragma unroll
        for (int t = 0; t < 16; ++t) v[t] = sp[(size_t)t * Bstr];
    };
    auto writeB = [&](bf16_t* bbuf, const float* v) {
        u32 p[8];
        #pragma unroll
        for (int t = 0; t < 8; ++t) p[t] = pack2(v[2 * t], v[2 * t + 1]);
        uint4 w0, w1;
        w0.x = p[0]; w0.y = p[1]; w0.z = p[2]; w0.w = p[3];
        w1.x = p[4]; w1.y = p[5]; w1.z = p[6]; w1.w = p[7];
        *(uint4*)(bbuf + (size_t)bn * BSTR + kb) = w0;
        *(uint4*)(bbuf + (size_t)bn * BSTR + kb + 8) = w1;
    };
    auto compute = [&](const bf16_t* abuf, const bf16_t* bbuf) {
        bf16x8 af[4], bfr[4];
        #pragma unroll
        for (int i = 0; i < 4; ++i) {
            const int row = m_off + i * 16 + l15;
            af[i] = *(const bf16x8*)(abuf + (size_t)row * 32 + (size_t)((lq ^ ((row >> 1) & 3)) * 8));
        }
        #pragma unroll
        for (int j = 0; j < 4; ++j) {
            const int n_ds = FUSED ? (wn * 32 + (j & 1) * 16 + (j >> 1) * 64)
                                   : (wn * 64 + j * 16);
            bfr[j] = *(const bf16x8*)(bbuf + (size_t)(n_ds + l15) * BSTR + lq * 8);
        }
        #pragma unroll
        for (int i = 0; i < 4; ++i)
            #pragma unroll
            for (int j = 0; j < 4; ++j)
                acc[i][j] = __builtin_amdgcn_mfma_f32_16x16x32_bf16(af[i], bfr[j], acc[i][j], 0, 0, 0);
    };

    float vBa[16], vBb[16];
    bf16_t *aR = &As[0][0], *aS = &As[1][0], *aT = &As[2][0];

    loadB(0, vBa);
    stageA(0, aR);
    asm volatile("s_waitcnt vmcnt(2)" ::: "memory");
    writeB(&Bs[0][0], vBa);
    loadB(1, vBb);
    stageA(1, aS);
    asm volatile("s_waitcnt lgkmcnt(0)" ::: "memory");
    __builtin_amdgcn_s_barrier();

    for (int t = 0; t < ksteps - 2; t += 2) {
        loadB(t + 2, vBa);
        asm volatile("s_waitcnt vmcnt(34)" ::: "memory");
        asm volatile("s_waitcnt lgkmcnt(0)" ::: "memory");
        __builtin_amdgcn_s_barrier();
        stageA(t + 2, aT);
        compute(aR, &Bs[0][0]);
        asm volatile("s_waitcnt vmcnt(20)" ::: "memory");
        writeB(&Bs[1][0], vBb);
        { bf16_t* tmp = aR; aR = aS; aS = aT; aT = tmp; }
        loadB(t + 3, vBb);
        asm volatile("s_waitcnt vmcnt(34)" ::: "memory");
        asm volatile("s_waitcnt lgkmcnt(0)" ::: "memory");
        __builtin_amdgcn_s_barrier();
        stageA(t + 3, aT);
        compute(aR, &Bs[1][0]);
        asm volatile("s_waitcnt vmcnt(20)" ::: "memory");
        writeB(&Bs[0][0], vBa);
        { bf16_t* tmp = aR; aR = aS; aS = aT; aT = tmp; }
    }

    asm volatile("s_waitcnt vmcnt(18)" ::: "memory");
    asm volatile("s_waitcnt lgkmcnt(0)" ::: "memory");
    __builtin_amdgcn_s_barrier();
    compute(aR, &Bs[0][0]);
    asm volatile("s_waitcnt vmcnt(2)" ::: "memory");
    writeB(&Bs[1][0], vBb);
    asm volatile("s_waitcnt vmcnt(0)" ::: "memory");
    asm volatile("s_waitcnt lgkmcnt(0)" ::: "memory");
    __builtin_amdgcn_s_barrier();
    compute(aS, &Bs[1][0]);

    if (FUSED) {
        #pragma unroll
        for (int i = 0; i < 4; ++i)
            #pragma unroll
            for (int j = 0; j < 2; ++j) {
                const int n = wn * 32 + j * 16 + l15;
                #pragma unroll
                for (int r = 0; r < 4; ++r) {
                    const int mm = m_off + i * 16 + lq * 4 + r;
                    Cout[(size_t)mm * Ostr + n] = (bf16_t)silu_mul(acc[i][j][r], acc[i][j + 2][r]);
                }
            }
    } else {
        #pragma unroll
        for (int i = 0; i < 4; ++i)
            #pragma unroll
            for (int j = 0; j < 4; ++j) {
                const int n = wn * 64 + j * 16 + l15;
                #pragma unroll
                for (int r = 0; r < 4; ++r) {
                    const int mm = m_off + i * 16 + lq * 4 + r;
                    Cout[(size_t)mm * Ostr + n] = (bf16_t)acc[i][j][r];
                }
            }
    }
}

// ---------------- combine: weighted scatter of routed + shared add ----------
__global__ void k_combine(const bf16_t* __restrict__ down, const int* __restrict__ sop,
                          const float* __restrict__ wts, float* __restrict__ y) {
    int t = blockIdx.x;
    int d0 = threadIdx.x * 8;
    float a[8] = {0, 0, 0, 0, 0, 0, 0, 0};
    #pragma unroll
    for (int k = 0; k < KK; ++k) {
        int slot = sop[t * KK + k];
        float w = wts[t * KK + k];
        bf16x8 v = *(const bf16x8*)(down + (size_t)slot * DD + d0);
        #pragma unroll
        for (int j = 0; j < 8; ++j) a[j] += w * (float)v[j];
    }
    #pragma unroll
    for (int s = 0; s < SS; ++s) {
        bf16x8 v = *(const bf16x8*)(down + ((size_t)EE * CC + (size_t)s * TT + t) * DD + d0);
        #pragma unroll
        for (int j = 0; j < 8; ++j) a[j] += (float)v[j];
    }
    float4 o0, o1;
    o0.x = a[0]; o0.y = a[1]; o0.z = a[2]; o0.w = a[3];
    o1.x = a[4]; o1.y = a[5]; o1.z = a[6]; o1.w = a[7];
    *(float4*)(y + (size_t)t * DD + d0) = o0;
    *(float4*)(y + (size_t)t * DD + d0 + 4) = o1;
}

extern "C" void kernel_launch(void* const* d_in, const int* in_sizes, int n_in,
                              void* d_out, int out_size, void* d_ws, size_t ws_size,
                              hipStream_t stream) {
    (void)in_sizes; (void)n_in; (void)out_size; (void)ws_size;
    const float* x      = (const float*)d_in[0];
    const float* wts    = (const float*)d_in[1];
    const float* w_gu   = (const float*)d_in[2];
    const float* w_dn   = (const float*)d_in[3];
    const float* w_gu_s = (const float*)d_in[4];
    const float* w_dn_s = (const float*)d_in[5];
    const int*   indices= (const int*)d_in[6];
    float* y = (float*)d_out;

    char* ws = (char*)d_ws;
    size_t off = 0;
    auto alloc = [&](size_t bytes) {
        void* p = ws + off;
        off = (off + bytes + 255) & ~(size_t)255;
        return p;
    };
    int*    counts = (int*)alloc((size_t)EE * 4);
    int*    tok    = (int*)alloc((size_t)EE * CC * 4);
    int*    sop    = (int*)alloc((size_t)TT * KK * 4);
    bf16_t* xall   = (bf16_t*)alloc((size_t)(EE * CC + TT) * DD * 2);
    bf16_t* actb   = (bf16_t*)alloc((size_t)(EE * CC + SS * TT) * FF * 2);
    bf16_t* dnout  = (bf16_t*)alloc((size_t)(EE * CC + SS * TT) * DD * 2);

    hipMemsetAsync(counts, 0, EE * 4, stream);
    k_dispatch<<<(TT * KK + 255) / 256, 256, 0, stream>>>(indices, counts, tok, sop);
    k_gather<<<EE * CC + TT, 256, 0, stream>>>(x, tok, xall);

    // ---- gate_up (K=DD, B stride 2*FF), silu fused -> actb ----
    k_gemm_r<true><<<EE * 22, 512, 0, stream>>>(xall, w_gu, actb, DD, 2 * FF, FF, 22);
    k_gemm_s<true><<<8 * 6 * 16, 256, 0, stream>>>(
        xall + (size_t)EE * CC * DD, w_gu_s, actb + (size_t)EE * CC * FF,
        DD, 2 * FF, FF, 0, 44, 6, 22);

    // ---- down (K=FF, B stride DD) -> dnout ----
    k_gemm_r<false><<<EE * 16, 512, 0, stream>>>(actb, w_dn, dnout, FF, DD, DD, 16);
    k_gemm_s<false><<<8 * 4 * 16, 256, 0, stream>>>(
        actb + (size_t)EE * CC * FF, w_dn_s, dnout + (size_t)EE * CC * DD,
        FF, DD, DD, TT, 32, 4, 16);

    k_combine<<<TT, 256, 0, stream>>>(dnout, sop, wts, y);
}